// Round 5
// baseline (256.637 us; speedup 1.0000x reference)
//
#include <hip/hip_runtime.h>
#include <math.h>

namespace {
constexpr int N = 8, C = 48, H = 96, W = 72;
constexpr int HW = H * W;        // 6912 = 108*64
constexpr int P = N * HW;        // 55296
constexpr float BN_EPS = 1e-5f;

// ws layout (float offsets)
constexpr int WS_WCAT = 0;                   // wcat[c][t][16]: 0..3 tm, 4..5 tr, 6..14 mk
constexpr int WCAT_SZ = C * 9 * 16;          // 6912
constexpr int WS_DWT  = WS_WCAT + WCAT_SZ;   // dwT[k][c][o], o contiguous
constexpr int DWT_SZ  = 9 * C * C;           // 20736
constexpr int WS_SC   = WS_DWT + DWT_SZ;     // bn scale[48]
constexpr int WS_BI   = WS_SC + C;           // bn bias2[48]
}

// ---------------------------------------------------------------------------
// Weight re-layout + BN fold.
// ---------------------------------------------------------------------------
__global__ void prep_kernel(const float* __restrict__ tm_w, const float* __restrict__ tr_w,
                            const float* __restrict__ mk_w, const float* __restrict__ dw,
                            const float* __restrict__ gamma, const float* __restrict__ beta,
                            const float* __restrict__ rmean, const float* __restrict__ rvar,
                            float* __restrict__ ws)
{
    int tid = blockIdx.x * blockDim.x + threadIdx.x;

    if (tid < WCAT_SZ) {
        int o  = tid & 15;
        int ct = tid >> 4;         // c*9 + t
        int c  = ct / 9;
        int t  = ct - c * 9;
        float v = 0.f;
        if (o < 4)       v = tm_w[(o * C + c) * 9 + t];
        else if (o < 6)  v = tr_w[((o - 4) * C + c) * 9 + t];
        else if (o < 15) v = mk_w[((o - 6) * C + c) * 9 + t];
        ws[WS_WCAT + tid] = v;
    }
    if (tid < DWT_SZ) {
        int o    = tid % C;
        int rest = tid / C;        // k*C + c
        int c    = rest % C;
        int k    = rest / C;
        ws[WS_DWT + tid] = dw[(o * C + c) * 9 + k];
    }
    if (tid < C) {
        float sc = gamma[tid] * rsqrtf(rvar[tid] + BN_EPS);
        ws[WS_SC + tid] = sc;
        ws[WS_BI + tid] = beta[tid] - rmean[tid] * sc;
    }
}

// ---------------------------------------------------------------------------
// Fused kernel: conv15 -> offsets in LDS -> deform-sample + contraction +
// BN + residual + ReLU. Block = 8 waves over the SAME 64 pixels; wave wv
// handles input channels 6*wv..6*wv+5 (wave-uniform -> SGPR weights).
// XCD swizzle: blockIdx&7 selects batch n, so each XCD's L2 holds one batch.
// ---------------------------------------------------------------------------
__global__ __launch_bounds__(512) void fused_kernel(
    const float* __restrict__ x,
    const float* __restrict__ tm_b, const float* __restrict__ tr_b,
    const float* __restrict__ mk_b,
    const float* __restrict__ ws,
    float* __restrict__ out)
{
    __shared__ float red[8][16][64];    // 32 KB, reused conv-reduce + 3-chunk epilogue
    __shared__ float offs[9][3][64];    // 6.9 KB: oy/ox/mk per k-tap

    int lane = threadIdx.x & 63;
    int wv   = __builtin_amdgcn_readfirstlane(threadIdx.x >> 6);  // 0..7, SGPR

    int b    = blockIdx.x;
    int n    = b & 7;                  // XCD-aligned batch
    int tile = b >> 3;                 // 0..107
    int hw   = tile * 64 + lane;
    int h    = hw / W;
    int w    = hw - h * W;

    const float* xn = x + (size_t)n * C * HW;

    // ================= conv phase: 15-channel 3x3 conv =================
    float cacc[15];
#pragma unroll
    for (int o = 0; o < 15; ++o) cacc[o] = 0.f;

    const float* wcat = ws + WS_WCAT;

#pragma unroll
    for (int cc = 0; cc < 6; ++cc) {
        int c = wv * 6 + cc;                      // wave-uniform
        const float* xc = xn + c * HW;
        float tap[9];
#pragma unroll
        for (int dy = -1; dy <= 1; ++dy) {
            int hh = h + dy;
            bool vy = (unsigned)hh < (unsigned)H;
#pragma unroll
            for (int dx = -1; dx <= 1; ++dx) {
                int ww = w + dx;
                bool v = vy && ((unsigned)ww < (unsigned)W);
                tap[(dy + 1) * 3 + (dx + 1)] = v ? xc[hh * W + ww] : 0.f;
            }
        }
#pragma unroll
        for (int t = 0; t < 9; ++t) {
            const float* wp = wcat + (c * 9 + t) * 16;   // SGPR base
            float tv = tap[t];
#pragma unroll
            for (int o = 0; o < 15; ++o) cacc[o] = fmaf(tv, wp[o], cacc[o]);
        }
    }

    // cross-wave reduce (15 rows of red)
#pragma unroll
    for (int o = 0; o < 15; ++o) red[wv][o][lane] = cacc[o];
    __syncthreads();

    float s15[15];
#pragma unroll
    for (int o = 0; o < 15; ++o) {
        float v = red[0][o][lane];
#pragma unroll
        for (int i = 1; i < 8; ++i) v += red[i][o][lane];
        s15[o] = v;
    }

    float t0 = s15[0] + tm_b[0], t1 = s15[1] + tm_b[1];
    float t2 = s15[2] + tm_b[2], t3 = s15[3] + tm_b[3];
    float r0 = s15[4] + tr_b[0], r1 = s15[5] + tr_b[1];

    for (int k = wv; k < 9; k += 8) {             // wave 0 does k=0,8
        float ry = (float)(k / 3) - 1.f;
        float rx = (float)(k % 3) - 1.f;
        offs[k][0][lane] = fmaf(t0, ry, fmaf(t1, rx, r0)) - ry;
        offs[k][1][lane] = fmaf(t2, ry, fmaf(t3, rx, r1)) - rx;
        offs[k][2][lane] = s15[6 + k] + mk_b[k];
    }
    __syncthreads();

    // ================= deform phase =================
    float acc[C];
#pragma unroll
    for (int o = 0; o < C; ++o) acc[o] = 0.f;

    const float* dwT = ws + WS_DWT;

#pragma unroll 1
    for (int k = 0; k < 9; ++k) {
        float o_y = offs[k][0][lane];
        float o_x = offs[k][1][lane];
        float m   = offs[k][2][lane];

        float py = (float)(h + k / 3 - 1) + o_y;
        float px = (float)(w + k % 3 - 1) + o_x;

        float y0f = floorf(py), x0f = floorf(px);
        float wy = py - y0f, wx = px - x0f;
        int y0 = (int)y0f, x0 = (int)x0f;
        int y1 = y0 + 1,  x1 = x0 + 1;

        bool vy0 = (unsigned)y0 < (unsigned)H;
        bool vy1 = (unsigned)y1 < (unsigned)H;
        bool vx0 = (unsigned)x0 < (unsigned)W;
        bool vx1 = (unsigned)x1 < (unsigned)W;

        int cy0 = min(max(y0, 0), H - 1) * W;
        int cy1 = min(max(y1, 0), H - 1) * W;
        int cx0 = min(max(x0, 0), W - 1);
        int cx1 = min(max(x1, 0), W - 1);

        float a00 = (vy0 && vx0) ? (1.f - wy) * (1.f - wx) * m : 0.f;
        float a01 = (vy0 && vx1) ? (1.f - wy) * wx * m         : 0.f;
        float a10 = (vy1 && vx0) ? wy * (1.f - wx) * m         : 0.f;
        float a11 = (vy1 && vx1) ? wy * wx * m                 : 0.f;

        int o00 = cy0 + cx0, o01 = cy0 + cx1, o10 = cy1 + cx0, o11 = cy1 + cx1;

        const float* dwk = dwT + k * C * C;
#pragma unroll
        for (int cc = 0; cc < 6; ++cc) {
            int c = wv * 6 + cc;                  // wave-uniform
            const float* xc = xn + c * HW;
            float s = xc[o00] * a00;
            s = fmaf(xc[o01], a01, s);
            s = fmaf(xc[o10], a10, s);
            s = fmaf(xc[o11], a11, s);
            const float* wp = dwk + c * C;        // SGPR base, s_load x48
#pragma unroll
            for (int o = 0; o < C; ++o) acc[o] = fmaf(s, wp[o], acc[o]);
        }
    }

    // 3-chunk cross-wave reduce (16 channels per chunk) + epilogue
    const float* sc = ws + WS_SC;
    const float* bi = ws + WS_BI;
    int base = n * C * HW + hw;

#pragma unroll 1
    for (int ch = 0; ch < 3; ++ch) {
        if (ch) __syncthreads();                  // protect LDS reuse
#pragma unroll
        for (int j = 0; j < 16; ++j) red[wv][j][lane] = acc[ch * 16 + j];
        __syncthreads();
#pragma unroll
        for (int j2 = 0; j2 < 2; ++j2) {
            int r = wv * 2 + j2;                  // row within chunk
            int o = ch * 16 + r;                  // output channel (wave-uniform)
            float v = red[0][r][lane];
#pragma unroll
            for (int i = 1; i < 8; ++i) v += red[i][r][lane];
            v = fmaf(v, sc[o], bi[o]) + x[base + o * HW];
            out[base + o * HW] = fmaxf(v, 0.f);
        }
    }
}

// ---------------------------------------------------------------------------
extern "C" void kernel_launch(void* const* d_in, const int* in_sizes, int n_in,
                              void* d_out, int out_size, void* d_ws, size_t ws_size,
                              hipStream_t stream)
{
    const float* x     = (const float*)d_in[0];
    const float* tm_w  = (const float*)d_in[1];
    const float* tm_b  = (const float*)d_in[2];
    const float* tr_w  = (const float*)d_in[3];
    const float* tr_b  = (const float*)d_in[4];
    const float* mk_w  = (const float*)d_in[5];
    const float* mk_b  = (const float*)d_in[6];
    const float* dw    = (const float*)d_in[7];
    const float* gamma = (const float*)d_in[8];
    const float* beta  = (const float*)d_in[9];
    const float* rmean = (const float*)d_in[10];
    const float* rvar  = (const float*)d_in[11];
    float* out = (float*)d_out;
    float* ws  = (float*)d_ws;

    hipLaunchKernelGGL(prep_kernel, dim3((DWT_SZ + 255) / 256), dim3(256), 0, stream,
                       tm_w, tr_w, mk_w, dw, gamma, beta, rmean, rvar, ws);
    hipLaunchKernelGGL(fused_kernel, dim3(P / 64), dim3(512), 0, stream,
                       x, tm_b, tr_b, mk_b, ws, out);
}